// Round 2
// baseline (888.455 us; speedup 1.0000x reference)
//
#include <hip/hip_runtime.h>
#include <hip/hip_bf16.h>

// B=500000, NGI=13, NLOC=10
// diagRAR[b] = (1/dt)*sum_g dw[b,g]*(n[g,:].R)^2
//            + k[b]  *sum_g dw[b,g]*((nx[b,0,g,:].R)^2 + (nx[b,1,g,:].R)^2)
// rr1[b] = r1_1[b] - diagRAR[b]*e_i[b]

#define NGI 13
#define NLOC 10
#define PERB (2 * NGI * NLOC) // 260 floats per b, = 65 float4 (16B aligned)

__global__ __launch_bounds__(256) void diag_rar_kernel(
    const float* __restrict__ e_i,
    const float* __restrict__ r1_1,
    const float* __restrict__ k,
    const float* __restrict__ dt,
    const float* __restrict__ n,
    const float* __restrict__ nx,
    const float* __restrict__ detwei,
    const float* __restrict__ R,
    float* __restrict__ out_diag,
    float* __restrict__ out_rr1,
    int B)
{
    // Broadcast small inputs (L1/L2-cached).
    float Rl[NLOC];
#pragma unroll
    for (int i = 0; i < NLOC; ++i) Rl[i] = R[i];

    // nR[g] = sum_i n[g,i]*R[i]; then keep nR[g]^2.
    float nR2[NGI];
#pragma unroll
    for (int g = 0; g < NGI; ++g) {
        float s = 0.f;
#pragma unroll
        for (int i = 0; i < NLOC; ++i) s += n[g * NLOC + i] * Rl[i];
        nR2[g] = s * s;
    }
    const float inv_dt = 1.0f / dt[0];

    for (int b = blockIdx.x * blockDim.x + threadIdx.x; b < B;
         b += gridDim.x * blockDim.x) {
        const float4* __restrict__ nxb =
            reinterpret_cast<const float4*>(nx + (size_t)b * PERB);

        float dot[2][NGI];
#pragma unroll
        for (int c = 0; c < 2; ++c)
#pragma unroll
            for (int g = 0; g < NGI; ++g) dot[c][g] = 0.f;

        // 260 floats = 65 float4; compile-time index decode.
#pragma unroll
        for (int j = 0; j < PERB / 4; ++j) {
            float4 v = nxb[j];
            float vv[4] = {v.x, v.y, v.z, v.w};
#pragma unroll
            for (int t = 0; t < 4; ++t) {
                const int flat = j * 4 + t;
                const int c = flat / (NGI * NLOC);
                const int rem = flat % (NGI * NLOC);
                const int g = rem / NLOC;
                const int i = rem % NLOC;
                dot[c][g] += vv[t] * Rl[i];
            }
        }

        const float* __restrict__ dwp = detwei + (size_t)b * NGI;
        float acc_k = 0.f, acc_n = 0.f;
#pragma unroll
        for (int g = 0; g < NGI; ++g) {
            const float dw = dwp[g];
            acc_k += dw * (dot[0][g] * dot[0][g] + dot[1][g] * dot[1][g]);
            acc_n += dw * nR2[g];
        }

        const float diag = acc_n * inv_dt + k[b] * acc_k;
        out_diag[b] = diag;
        out_rr1[b] = r1_1[b] - diag * e_i[b];
    }
}

extern "C" void kernel_launch(void* const* d_in, const int* in_sizes, int n_in,
                              void* d_out, int out_size, void* d_ws, size_t ws_size,
                              hipStream_t stream) {
    const float* e_i    = (const float*)d_in[0];
    const float* r1_1   = (const float*)d_in[1];
    const float* k      = (const float*)d_in[2];
    const float* dt     = (const float*)d_in[3];
    const float* n      = (const float*)d_in[4];
    const float* nx     = (const float*)d_in[5];
    const float* detwei = (const float*)d_in[6];
    const float* R      = (const float*)d_in[7];

    const int B = in_sizes[0]; // e_i is (B,1)
    float* out_diag = (float*)d_out;
    float* out_rr1  = (float*)d_out + B;

    const int block = 256;
    const int grid = (B + block - 1) / block;
    diag_rar_kernel<<<grid, block, 0, stream>>>(
        e_i, r1_1, k, dt, n, nx, detwei, R, out_diag, out_rr1, B);
}